// Round 4
// baseline (2728.418 us; speedup 1.0000x reference)
//
#include <hip/hip_runtime.h>
#include <cstdint>
#include <cstddef>

#define NUM_TOK 16384
#define HID     4096
#define NEXP    64
#define TOPK    8
#define TB      32              // tokens per block
#define XROW    68              // staged row stride (floats): 64 + 4 pad, 272 B (16B-aligned)

// ---------------- transpose W [E][H] -> Wt [H][E], coalesced both sides ----------------
__global__ __launch_bounds__(256) void transpose_w(const float* __restrict__ W,
                                                   float* __restrict__ Wt) {
    __shared__ float tile[64][65];
    const int tid = threadIdx.x;
    const int k0  = blockIdx.x * 64;
#pragma unroll
    for (int m = 0; m < 4; ++m) {
        int e = m * 16 + (tid >> 4);
        int k = (tid & 15) * 4;
        float4 v = *reinterpret_cast<const float4*>(W + (size_t)e * HID + k0 + k);
        tile[e][k + 0] = v.x; tile[e][k + 1] = v.y;
        tile[e][k + 2] = v.z; tile[e][k + 3] = v.w;
    }
    __syncthreads();
#pragma unroll
    for (int m = 0; m < 4; ++m) {
        int k = m * 16 + (tid >> 4);
        int e = (tid & 15) * 4;
        float4 v = make_float4(tile[e + 0][k], tile[e + 1][k],
                               tile[e + 2][k], tile[e + 3][k]);
        *reinterpret_cast<float4*>(Wt + (size_t)(k0 + k) * NEXP + e) = v;
    }
}

__device__ __forceinline__ float wave_sum(float v) {
#pragma unroll
    for (int off = 32; off >= 1; off >>= 1)
        v += __shfl_xor(v, off, 64);
    return v;
}

// ---------------- fused router ----------------
// grid 512 x 256 thr (4 waves). Block owns 32 tokens; wave s = k-slice s (1024 k).
// Lane tile 4 tok x 8 exp: tokens lr+8i (lr = lane>>3, stride-8 => conflict-free LDS
// reads at XROW=68), experts e0 = (lane&7)*8. X reg-staged into LDS (T14 async split:
// issue loads for c+1, compute c, barrier, ds_write, barrier). W read directly from
// L2-resident Wt (global float4 pairs, reused across 4 tokens in registers).
// NUMERICS (R2-proven, FROZEN): per (t,e): chunk = 64-k fmaf chain (part),
// slice = 16 chunks summed ascending (sliceSum += part), total = ((s0+s1)+s2)+s3.
__global__ __launch_bounds__(256, 2) void router_fused(
    const float* __restrict__ hidden,   // [T][H]
    const float* __restrict__ Wt,       // [H][E]
    float* __restrict__ out_idx, float* __restrict__ out_gates,
    float* __restrict__ gImp, float* __restrict__ gCnt) {
    __shared__ __align__(16) float Xs[4][TB * XROW];   // 34,816 B; reused as [s][t][e] partials

    const int tid   = threadIdx.x;
    const int lane  = tid & 63;
    const int s     = __builtin_amdgcn_readfirstlane(tid >> 6);   // wave = k-slice
    const int lr    = lane >> 3;
    const int e0    = (lane & 7) * 8;
    const int T0    = blockIdx.x * TB;
    const int kbase = s * 1024;
    const int srow  = lane >> 4;         // staging: 4 rows per iter
    const int scol  = (lane & 15) * 4;   // 16 lanes x 16 B = one 64-float row

    float part[4][8], sliceSum[4][8];
#pragma unroll
    for (int i = 0; i < 4; ++i)
#pragma unroll
        for (int j = 0; j < 8; ++j) sliceSum[i][j] = 0.0f;

    float4 stg[8];
    // prologue: stage chunk 0
#pragma unroll
    for (int m = 0; m < 8; ++m)
        stg[m] = *reinterpret_cast<const float4*>(
            hidden + (size_t)(T0 + m * 4 + srow) * HID + kbase + scol);
#pragma unroll
    for (int m = 0; m < 8; ++m)
        *reinterpret_cast<float4*>(&Xs[s][(m * 4 + srow) * XROW + scol]) = stg[m];
    __syncthreads();

    for (int c = 0; c < 16; ++c) {
        if (c + 1 < 16) {                // issue next-chunk loads early (latency hidden)
#pragma unroll
            for (int m = 0; m < 8; ++m)
                stg[m] = *reinterpret_cast<const float4*>(
                    hidden + (size_t)(T0 + m * 4 + srow) * HID + kbase + (c + 1) * 64 + scol);
        }
        const float* __restrict__ xp = &Xs[s][0];
        const float* __restrict__ wb = Wt + (size_t)(kbase + c * 64) * NEXP + e0;

#pragma unroll
        for (int i = 0; i < 4; ++i)
#pragma unroll
            for (int j = 0; j < 8; ++j) part[i][j] = 0.0f;

#pragma unroll
        for (int k4 = 0; k4 < 16; ++k4) {
            float4 xv0 = *reinterpret_cast<const float4*>(xp + (lr +  0) * XROW + k4 * 4);
            float4 xv1 = *reinterpret_cast<const float4*>(xp + (lr +  8) * XROW + k4 * 4);
            float4 xv2 = *reinterpret_cast<const float4*>(xp + (lr + 16) * XROW + k4 * 4);
            float4 xv3 = *reinterpret_cast<const float4*>(xp + (lr + 24) * XROW + k4 * 4);
            float xa[4][4] = {{xv0.x, xv0.y, xv0.z, xv0.w},
                              {xv1.x, xv1.y, xv1.z, xv1.w},
                              {xv2.x, xv2.y, xv2.z, xv2.w},
                              {xv3.x, xv3.y, xv3.z, xv3.w}};
#pragma unroll
            for (int j2 = 0; j2 < 4; ++j2) {         // k = kbase + c*64 + k4*4 + j2, ascending
                float4 wA = *reinterpret_cast<const float4*>(wb + (size_t)(k4 * 4 + j2) * NEXP);
                float4 wB = *reinterpret_cast<const float4*>(wb + (size_t)(k4 * 4 + j2) * NEXP + 4);
                float wv[8] = {wA.x, wA.y, wA.z, wA.w, wB.x, wB.y, wB.z, wB.w};
#pragma unroll
                for (int i = 0; i < 4; ++i) {
                    float x = xa[i][j2];
#pragma unroll
                    for (int j = 0; j < 8; ++j)
                        part[i][j] = fmaf(x, wv[j], part[i][j]);   // k-ascending chain
                }
            }
        }
#pragma unroll
        for (int i = 0; i < 4; ++i)
#pragma unroll
            for (int j = 0; j < 8; ++j) sliceSum[i][j] += part[i][j];   // two-level sum

        __syncthreads();                 // all reads of Xs done
        if (c + 1 < 16) {
#pragma unroll
            for (int m = 0; m < 8; ++m)
                *reinterpret_cast<float4*>(&Xs[s][(m * 4 + srow) * XROW + scol]) = stg[m];
        }
        __syncthreads();                 // writes visible before next reads
    }

    // -------- slice partials -> LDS pane [s][t][e] (reuse Xs) --------
#pragma unroll
    for (int i = 0; i < 4; ++i) {
        int t = lr + 8 * i;
        *reinterpret_cast<float4*>(&Xs[s][t * XROW + e0]) =
            make_float4(sliceSum[i][0], sliceSum[i][1], sliceSum[i][2], sliceSum[i][3]);
        *reinterpret_cast<float4*>(&Xs[s][t * XROW + e0 + 4]) =
            make_float4(sliceSum[i][4], sliceSum[i][5], sliceSum[i][6], sliceSum[i][7]);
    }
    __syncthreads();

    // -------- finalize: thread t (< 32) owns token t (R2/R3-proven path) --------
    float sc[NEXP];
#pragma unroll
    for (int e = 0; e < NEXP; ++e) sc[e] = 0.0f;
    unsigned long long used = 0ull;

    if (tid < TB) {
        const int t = tid;
#pragma unroll
        for (int e4 = 0; e4 < NEXP / 4; ++e4) {      // ascending slice fold ((s0+s1)+s2)+s3
            float4 v0 = *reinterpret_cast<const float4*>(&Xs[0][t * XROW + e4 * 4]);
            float4 v1 = *reinterpret_cast<const float4*>(&Xs[1][t * XROW + e4 * 4]);
            float4 v2 = *reinterpret_cast<const float4*>(&Xs[2][t * XROW + e4 * 4]);
            float4 v3 = *reinterpret_cast<const float4*>(&Xs[3][t * XROW + e4 * 4]);
            sc[e4 * 4 + 0] = ((v0.x + v1.x) + v2.x) + v3.x;
            sc[e4 * 4 + 1] = ((v0.y + v1.y) + v2.y) + v3.y;
            sc[e4 * 4 + 2] = ((v0.z + v1.z) + v2.z) + v3.z;
            sc[e4 * 4 + 3] = ((v0.w + v1.w) + v2.w) + v3.w;
        }

        float m = sc[0];
#pragma unroll
        for (int e = 1; e < NEXP; ++e) m = fmaxf(m, sc[e]);
        float sum = 0.0f;
#pragma unroll
        for (int e = 0; e < NEXP; ++e) { sc[e] = expf(sc[e] - m); sum += sc[e]; }
#pragma unroll
        for (int e = 0; e < NEXP; ++e) sc[e] = sc[e] / sum;    // softmax scores

        // top-8: masked argmax, strict '>', ascending e => lowest index on ties
        float g[TOPK];
        float fid[TOPK];
#pragma unroll
        for (int r = 0; r < TOPK; ++r) {
            float best = -1.0f;
            int   bi   = 0;
#pragma unroll
            for (int e = 0; e < NEXP; ++e) {
                bool ok = (((used >> e) & 1ull) == 0ull) && (sc[e] > best);
                best = ok ? sc[e] : best;
                bi   = ok ? e : bi;
            }
            used |= (1ull << bi);
            g[r]   = best;
            fid[r] = (float)bi;
        }
        float gsum = ((g[0] + g[1]) + (g[2] + g[3])) +
                     ((g[4] + g[5]) + (g[6] + g[7])) + 1e-6f;
        float inv = 1.0f / gsum;

        int tg = T0 + t;
        float4 i0 = make_float4(fid[0], fid[1], fid[2], fid[3]);
        float4 i1 = make_float4(fid[4], fid[5], fid[6], fid[7]);
        float4 g0 = make_float4(g[0] * inv, g[1] * inv, g[2] * inv, g[3] * inv);
        float4 g1 = make_float4(g[4] * inv, g[5] * inv, g[6] * inv, g[7] * inv);
        *reinterpret_cast<float4*>(out_idx   + (size_t)tg * 8)     = i0;
        *reinterpret_cast<float4*>(out_idx   + (size_t)tg * 8 + 4) = i1;
        *reinterpret_cast<float4*>(out_gates + (size_t)tg * 8)     = g0;
        *reinterpret_cast<float4*>(out_gates + (size_t)tg * 8 + 4) = g1;
    }

    // aux: importance + counts over the block's 32 tokens (lanes >= 32: sc=0, used=0)
    if (tid < 64) {
        float myImp = 0.0f, myCnt = 0.0f;
#pragma unroll
        for (int e = 0; e < NEXP; ++e) {
            float se = wave_sum(sc[e]);
            unsigned long long b = __ballot(((used >> e) & 1ull) != 0ull);
            if (lane == e) { myImp = se; myCnt = (float)__popcll(b); }
        }
        atomicAdd(&gImp[lane], myImp);
        atomicAdd(&gCnt[lane], myCnt);
    }
}

// ---------------- aux loss ----------------
__global__ __launch_bounds__(64) void aux_kernel(const float* __restrict__ gImp,
                                                 const float* __restrict__ gCnt,
                                                 float* __restrict__ out_aux) {
    int lane = threadIdx.x;
    float v = gImp[lane] * gCnt[lane];
    v = wave_sum(v);
    if (lane == 0)
        *out_aux = v * (0.01f / (float)NUM_TOK);
}

extern "C" void kernel_launch(void* const* d_in, const int* in_sizes, int n_in,
                              void* d_out, int out_size, void* d_ws, size_t ws_size,
                              hipStream_t stream) {
    const float* hidden = (const float*)d_in[0];   // [4,4096,4096] f32
    const float* W      = (const float*)d_in[1];   // [64,4096] f32

    float* out       = (float*)d_out;
    float* out_idx   = out;
    float* out_gates = out + (size_t)NUM_TOK * TOPK;
    float* out_aux   = out + (size_t)2 * NUM_TOK * TOPK;

    float* Wt   = (float*)d_ws;                          // 1 MiB
    float* gImp = (float*)((char*)d_ws + (1 << 20));     // 64 f32
    float* gCnt = gImp + NEXP;

    // NOTE: no ws_size-dependent branching — identical work on every call.
    hipMemsetAsync(gImp, 0, 2 * NEXP * sizeof(float), stream);
    transpose_w<<<HID / 64, 256, 0, stream>>>(W, Wt);
    router_fused<<<NUM_TOK / TB, 256, 0, stream>>>(hidden, Wt, out_idx, out_gates,
                                                   gImp, gCnt);
    aux_kernel<<<1, 64, 0, stream>>>(gImp, gCnt, out_aux);
}

// Round 5
// 816.538 us; speedup vs baseline: 3.3414x; 3.3414x over previous
//
#include <hip/hip_runtime.h>
#include <cstdint>
#include <cstddef>

#define NUM_TOK 16384
#define HID     4096
#define NEXP    64
#define TOPK    8
#define TPB     16              // tokens per block
#define XROW    68              // staged row stride (floats): 64 + 4 pad, 272 B (16B-aligned)

typedef const float __attribute__((address_space(1)))* gptr_t;
typedef float __attribute__((address_space(3)))* lptr_t;

// ---------------- transpose W [E][H] -> Wt [H][E], coalesced both sides ----------------
__global__ __launch_bounds__(256) void transpose_w(const float* __restrict__ W,
                                                   float* __restrict__ Wt) {
    __shared__ float tile[64][65];
    const int tid = threadIdx.x;
    const int k0  = blockIdx.x * 64;
#pragma unroll
    for (int m = 0; m < 4; ++m) {
        int e = m * 16 + (tid >> 4);
        int k = (tid & 15) * 4;
        float4 v = *reinterpret_cast<const float4*>(W + (size_t)e * HID + k0 + k);
        tile[e][k + 0] = v.x; tile[e][k + 1] = v.y;
        tile[e][k + 2] = v.z; tile[e][k + 3] = v.w;
    }
    __syncthreads();
#pragma unroll
    for (int m = 0; m < 4; ++m) {
        int k = m * 16 + (tid >> 4);
        int e = (tid & 15) * 4;
        float4 v = make_float4(tile[e + 0][k], tile[e + 1][k],
                               tile[e + 2][k], tile[e + 3][k]);
        *reinterpret_cast<float4*>(Wt + (size_t)(k0 + k) * NEXP + e) = v;
    }
}

__device__ __forceinline__ float wave_sum(float v) {
#pragma unroll
    for (int off = 32; off >= 1; off >>= 1)
        v += __shfl_xor(v, off, 64);
    return v;
}

// ---------------- fused router ----------------
// grid 1024 x 256 thr (4 waves). Block owns 16 tokens; wave s = k-slice s (1024 k).
// Lane tile 2 tok x 8 exp: tokens lr, lr+8 (lr = lane>>3), experts e0 = (lane&7)*8.
// X: per-wave pane in LDS via global_load_lds (double-buffered, 1 barrier/chunk,
// zero register cost). W: per-lane global float4 pairs from L2-resident Wt
// (VMEM pipe — keeps the W stream OFF the LDS port, the R3 bottleneck).
// Register state deliberately small (part[2][8] + sliceSum[2][8] = 32) — R4's
// spill (VGPR cap 128, 4.9 GB scratch writes) came from 128 floats of state.
// NUMERICS (R2/R3/R4-proven, FROZEN): per (t,e): chunk = 64-k fmaf chain (part),
// slice = 16 chunks summed ascending (sliceSum += part), total = ((s0+s1)+s2)+s3.
__global__ __launch_bounds__(256, 4) void router_fused(
    const float* __restrict__ hidden,   // [T][H]
    const float* __restrict__ Wt,       // [H][E]
    float* __restrict__ out_idx, float* __restrict__ out_gates,
    float* __restrict__ gImp, float* __restrict__ gCnt) {
    __shared__ __align__(16) float Xs[4][2][TPB * XROW];   // 34,816 B

    const int tid   = threadIdx.x;
    const int lane  = tid & 63;
    const int s     = __builtin_amdgcn_readfirstlane(tid >> 6);   // wave = k-slice
    const int lr    = lane >> 3;
    const int e0    = (lane & 7) * 8;
    const int T0    = blockIdx.x * TPB;
    const int kbase = s * 1024;

    auto stage = [&](int c) {
        int buf = c & 1;
#pragma unroll
        for (int r = 0; r < TPB; ++r) {
            const float* src = hidden + (size_t)(T0 + r) * HID + kbase + c * 64 + lane;
            __builtin_amdgcn_global_load_lds((gptr_t)src,
                (lptr_t)(&Xs[s][buf][r * XROW + lane]), 4, 0, 0);
        }
    };

    float part[2][8], sliceSum[2][8];
#pragma unroll
    for (int i = 0; i < 2; ++i)
#pragma unroll
        for (int j = 0; j < 8; ++j) sliceSum[i][j] = 0.0f;

    stage(0);
    for (int c = 0; c < 16; ++c) {
        __syncthreads();                 // drains stage(c); fences buffer reuse
        if (c + 1 < 16) stage(c + 1);
        const float* __restrict__ xp = &Xs[s][c & 1][0];
        const float* __restrict__ wb = Wt + (size_t)(kbase + c * 64) * NEXP + e0;

#pragma unroll
        for (int i = 0; i < 2; ++i)
#pragma unroll
            for (int j = 0; j < 8; ++j) part[i][j] = 0.0f;

#pragma unroll
        for (int k4 = 0; k4 < 16; ++k4) {
            float4 xv0 = *reinterpret_cast<const float4*>(xp + (lr + 0) * XROW + k4 * 4);
            float4 xv1 = *reinterpret_cast<const float4*>(xp + (lr + 8) * XROW + k4 * 4);
            float xa0[4] = {xv0.x, xv0.y, xv0.z, xv0.w};
            float xa1[4] = {xv1.x, xv1.y, xv1.z, xv1.w};
#pragma unroll
            for (int j2 = 0; j2 < 4; ++j2) {      // k = kbase + c*64 + k4*4 + j2, ascending
                float4 wA = *reinterpret_cast<const float4*>(wb + (size_t)(k4 * 4 + j2) * NEXP);
                float4 wB = *reinterpret_cast<const float4*>(wb + (size_t)(k4 * 4 + j2) * NEXP + 4);
                float x0 = xa0[j2], x1 = xa1[j2];
                part[0][0] = fmaf(x0, wA.x, part[0][0]);
                part[0][1] = fmaf(x0, wA.y, part[0][1]);
                part[0][2] = fmaf(x0, wA.z, part[0][2]);
                part[0][3] = fmaf(x0, wA.w, part[0][3]);
                part[0][4] = fmaf(x0, wB.x, part[0][4]);
                part[0][5] = fmaf(x0, wB.y, part[0][5]);
                part[0][6] = fmaf(x0, wB.z, part[0][6]);
                part[0][7] = fmaf(x0, wB.w, part[0][7]);
                part[1][0] = fmaf(x1, wA.x, part[1][0]);
                part[1][1] = fmaf(x1, wA.y, part[1][1]);
                part[1][2] = fmaf(x1, wA.z, part[1][2]);
                part[1][3] = fmaf(x1, wA.w, part[1][3]);
                part[1][4] = fmaf(x1, wB.x, part[1][4]);
                part[1][5] = fmaf(x1, wB.y, part[1][5]);
                part[1][6] = fmaf(x1, wB.z, part[1][6]);
                part[1][7] = fmaf(x1, wB.w, part[1][7]);
            }
        }
#pragma unroll
        for (int i = 0; i < 2; ++i)
#pragma unroll
            for (int j = 0; j < 8; ++j) sliceSum[i][j] += part[i][j];   // two-level sum
    }

    // -------- slice partials -> LDS pane [s][buf0][t][e] (own pane: no pre-barrier) --------
#pragma unroll
    for (int i = 0; i < 2; ++i) {
        int t = lr + 8 * i;
        *reinterpret_cast<float4*>(&Xs[s][0][t * XROW + e0]) =
            make_float4(sliceSum[i][0], sliceSum[i][1], sliceSum[i][2], sliceSum[i][3]);
        *reinterpret_cast<float4*>(&Xs[s][0][t * XROW + e0 + 4]) =
            make_float4(sliceSum[i][4], sliceSum[i][5], sliceSum[i][6], sliceSum[i][7]);
    }
    __syncthreads();

    // -------- finalize: thread t (< 16) owns token t (R2/R3-proven path) --------
    float sc[NEXP];
#pragma unroll
    for (int e = 0; e < NEXP; ++e) sc[e] = 0.0f;
    unsigned long long used = 0ull;

    if (tid < TPB) {
        const int t = tid;
#pragma unroll
        for (int e4 = 0; e4 < NEXP / 4; ++e4) {   // ascending slice fold ((s0+s1)+s2)+s3
            float4 v0 = *reinterpret_cast<const float4*>(&Xs[0][0][t * XROW + e4 * 4]);
            float4 v1 = *reinterpret_cast<const float4*>(&Xs[1][0][t * XROW + e4 * 4]);
            float4 v2 = *reinterpret_cast<const float4*>(&Xs[2][0][t * XROW + e4 * 4]);
            float4 v3 = *reinterpret_cast<const float4*>(&Xs[3][0][t * XROW + e4 * 4]);
            sc[e4 * 4 + 0] = ((v0.x + v1.x) + v2.x) + v3.x;
            sc[e4 * 4 + 1] = ((v0.y + v1.y) + v2.y) + v3.y;
            sc[e4 * 4 + 2] = ((v0.z + v1.z) + v2.z) + v3.z;
            sc[e4 * 4 + 3] = ((v0.w + v1.w) + v2.w) + v3.w;
        }

        float m = sc[0];
#pragma unroll
        for (int e = 1; e < NEXP; ++e) m = fmaxf(m, sc[e]);
        float sum = 0.0f;
#pragma unroll
        for (int e = 0; e < NEXP; ++e) { sc[e] = expf(sc[e] - m); sum += sc[e]; }
#pragma unroll
        for (int e = 0; e < NEXP; ++e) sc[e] = sc[e] / sum;    // softmax scores

        // top-8: masked argmax, strict '>', ascending e => lowest index on ties
        float g[TOPK];
        float fid[TOPK];
#pragma unroll
        for (int r = 0; r < TOPK; ++r) {
            float best = -1.0f;
            int   bi   = 0;
#pragma unroll
            for (int e = 0; e < NEXP; ++e) {
                bool ok = (((used >> e) & 1ull) == 0ull) && (sc[e] > best);
                best = ok ? sc[e] : best;
                bi   = ok ? e : bi;
            }
            used |= (1ull << bi);
            g[r]   = best;
            fid[r] = (float)bi;
        }
        float gsum = ((g[0] + g[1]) + (g[2] + g[3])) +
                     ((g[4] + g[5]) + (g[6] + g[7])) + 1e-6f;
        float inv = 1.0f / gsum;

        int tg = T0 + t;
        float4 i0 = make_float4(fid[0], fid[1], fid[2], fid[3]);
        float4 i1 = make_float4(fid[4], fid[5], fid[6], fid[7]);
        float4 g0 = make_float4(g[0] * inv, g[1] * inv, g[2] * inv, g[3] * inv);
        float4 g1 = make_float4(g[4] * inv, g[5] * inv, g[6] * inv, g[7] * inv);
        *reinterpret_cast<float4*>(out_idx   + (size_t)tg * 8)     = i0;
        *reinterpret_cast<float4*>(out_idx   + (size_t)tg * 8 + 4) = i1;
        *reinterpret_cast<float4*>(out_gates + (size_t)tg * 8)     = g0;
        *reinterpret_cast<float4*>(out_gates + (size_t)tg * 8 + 4) = g1;
    }

    // aux: importance + counts over the block's 16 tokens (lanes >= 16: sc=0, used=0)
    if (tid < 64) {
        float myImp = 0.0f, myCnt = 0.0f;
#pragma unroll
        for (int e = 0; e < NEXP; ++e) {
            float se = wave_sum(sc[e]);
            unsigned long long b = __ballot(((used >> e) & 1ull) != 0ull);
            if (lane == e) { myImp = se; myCnt = (float)__popcll(b); }
        }
        atomicAdd(&gImp[lane], myImp);
        atomicAdd(&gCnt[lane], myCnt);
    }
}

// ---------------- aux loss ----------------
__global__ __launch_bounds__(64) void aux_kernel(const float* __restrict__ gImp,
                                                 const float* __restrict__ gCnt,
                                                 float* __restrict__ out_aux) {
    int lane = threadIdx.x;
    float v = gImp[lane] * gCnt[lane];
    v = wave_sum(v);
    if (lane == 0)
        *out_aux = v * (0.01f / (float)NUM_TOK);
}

extern "C" void kernel_launch(void* const* d_in, const int* in_sizes, int n_in,
                              void* d_out, int out_size, void* d_ws, size_t ws_size,
                              hipStream_t stream) {
    const float* hidden = (const float*)d_in[0];   // [4,4096,4096] f32
    const float* W      = (const float*)d_in[1];   // [64,4096] f32

    float* out       = (float*)d_out;
    float* out_idx   = out;
    float* out_gates = out + (size_t)NUM_TOK * TOPK;
    float* out_aux   = out + (size_t)2 * NUM_TOK * TOPK;

    float* Wt   = (float*)d_ws;                          // 1 MiB
    float* gImp = (float*)((char*)d_ws + (1 << 20));     // 64 f32
    float* gCnt = gImp + NEXP;

    // NOTE: no ws_size-dependent branching — identical work on every call.
    hipMemsetAsync(gImp, 0, 2 * NEXP * sizeof(float), stream);
    transpose_w<<<HID / 64, 256, 0, stream>>>(W, Wt);
    router_fused<<<NUM_TOK / TPB, 256, 0, stream>>>(hidden, Wt, out_idx, out_gates,
                                                    gImp, gCnt);
    aux_kernel<<<1, 64, 0, stream>>>(gImp, gCnt, out_aux);
}